// Round 2
// baseline (1297.078 us; speedup 1.0000x reference)
//
#include <hip/hip_runtime.h>

// TemporalCausalMaps on MI355X (gfx950), round 5.
// One sample per block, TWO waves per block (128 threads).
//  - grid 2048 blocks x 2 waves = 16 waves/CU (was 8): latency hiding.
//  - wide stages (input gates, cm1, cm2, proj, gproj) split the time axis
//    across the two waves.
//  - GRU hidden recurrence on wave 0 only, half-split across lane pairs
//    (j, j+32): 12-deep partial dots + __shfl_xor(32) combine, no barriers
//    inside the t loop (single-wave DS ops are compiler-ordered).
//  - FIX vs round 4: bhh bias was double-counted (both halves added it
//    before the shfl combine). Half 1 now starts its partials at 0.

#define NT 128

__device__ __forceinline__ float sigm(float x) { return 1.0f / (1.0f + __expf(-x)); }
__device__ __forceinline__ float tanh_fast(float x) {
  x = fminf(15.0f, fmaxf(-15.0f, x));
  float e = __expf(2.0f * x);
  return (e - 1.0f) / (e + 1.0f);
}
__device__ __forceinline__ float leaky(float x) { return x >= 0.0f ? x : 0.01f * x; }

template <int N4>
__device__ __forceinline__ float dotv(const float* __restrict__ w, const float* h) {
  const float4* w4 = reinterpret_cast<const float4*>(w);
  const float4* h4 = reinterpret_cast<const float4*>(h);
  float acc = 0.0f;
#pragma unroll
  for (int i = 0; i < N4; ++i) {
    float4 a = w4[i], b = h4[i];
    acc = fmaf(a.x, b.x, acc); acc = fmaf(a.y, b.y, acc);
    acc = fmaf(a.z, b.z, acc); acc = fmaf(a.w, b.w, acc);
  }
  return acc;
}

// LDS layout (floats), 16B-aligned offsets. Total 3280 floats = 13120 B.
//  s_x   [8][48]  @0       s_h  [8][24] @384    s_g   [8][24] @576
//  s_gi  [8][72]  @768     s_y  [8][24] @1344   s_hid [2][24] @1536
//  s_d1  [8][68]  @1584    s_d2 [8][68] @2128   s_dec [8][8]  @2672
//  s_ch  [8][68]  @2736    (cond relu hidden, stride 68 = conflict-free)
__global__ __launch_bounds__(NT, 4) void tcm_kernel(
    const float* __restrict__ z,
    const float* __restrict__ cond_w1, const float* __restrict__ cond_b1,
    const float* __restrict__ cond_w2, const float* __restrict__ cond_b2,
    const float* __restrict__ proj_w, const float* __restrict__ proj_b,
    const float* __restrict__ gpw, const float* __restrict__ gpb,
    const float* __restrict__ gru_wih, const float* __restrict__ gru_whh,
    const float* __restrict__ gru_bih, const float* __restrict__ gru_bhh,
    const float* __restrict__ cm_w1, const float* __restrict__ cm_b1,
    const float* __restrict__ cm_w2, const float* __restrict__ cm_b2,
    const float* __restrict__ cm_w3, const float* __restrict__ cm_b3,
    const int* __restrict__ endw,
    float* __restrict__ out, int Btot) {
  __shared__ __align__(16) float lds[3280];
  float* s_x   = lds;
  float* s_h   = lds + 384;
  float* s_g   = lds + 576;
  float* s_gi  = lds + 768;
  float* s_y   = lds + 1344;
  float* s_hid = lds + 1536;
  float* s_d1  = lds + 1584;   // stride 68
  float* s_d2  = lds + 2128;   // stride 68
  float* s_dec = lds + 2672;
  float* s_ch  = lds + 2736;   // stride 68

  const int tid  = threadIdx.x;
  const int lane = tid & 63;
  const int wid  = tid >> 6;
  const int b = blockIdx.x;
  const int T = endw[0];

  if (tid < 64) s_dec[tid] = 0.0f;  // avoid garbage in gated paths
  __syncthreads();

#pragma unroll 1
  for (int idx = 0; idx < T; ++idx) {
    const int L = idx + 1;
#pragma unroll 1
    for (int n = 0; n < 8; ++n) {
      // ---- stage 1a: copy z prefix (float4) into s_x[t][0:32]  (L*8 <= 64)
      if (tid < L * 8) {
        const float4* z4 = reinterpret_cast<const float4*>(
            z + ((size_t)n * Btot + b) * 8 * 32);
        int t = tid >> 3, q = tid & 7;
        reinterpret_cast<float4*>(s_x)[t * 12 + q] = z4[t * 8 + q];
      }
      // ---- stage 1b phase 1: cond relu hidden, item = (t, src, k)
      if (idx > 0) {
#pragma unroll 1
        for (int it = tid; it < L * 64; it += NT) {
          int t = it >> 6, r = it & 63, src = r >> 5, k = r & 31;
          int nn = (src == 0) ? n : (n > 0 ? n - 1 : 0);
          float w1v = cond_w1[nn * 32 + k];
          float b1v = cond_b1[nn * 32 + k];
          float xv = s_dec[nn * 8 + t];
          s_ch[t * 68 + r] = fmaxf(fmaf(xv, w1v, b1v), 0.0f);
        }
      }
      __syncthreads();
      // ---- stage 1b phase 2: cond output dot32 -> s_x[t][32:48] (L*16 <= 128)
      if (tid < L * 16) {
        int t = tid >> 4, c = tid & 15;
        float v = 0.0f;
        if (c < 8) {
          if (t < idx)
            v = cond_b2[n * 8 + c] +
                dotv<8>(cond_w2 + (size_t)(n * 8 + c) * 32, s_ch + t * 68);
        } else {
          if (n > 0 && idx > 0)
            v = cond_b2[(n - 1) * 8 + (c - 8)] +
                dotv<8>(cond_w2 + (size_t)((n - 1) * 8 + c - 8) * 32,
                        s_ch + t * 68 + 32);
        }
        s_x[t * 48 + 32 + c] = v;
      }
      __syncthreads();
      // ---- proj -> leaky: slot = t mod 4, j = lane&31 (24 active)
      {
        int slot = tid >> 5, j = tid & 31;
        if (j < 24) {
#pragma unroll 1
          for (int t = slot; t < L; t += 4) {
            float acc = proj_b[n * 24 + j] +
                        dotv<12>(proj_w + (size_t)(n * 24 + j) * 48, s_x + t * 48);
            s_h[t * 24 + j] = leaky(acc);
          }
        }
      }
      __syncthreads();
      // ---- gru_proj
      {
        int slot = tid >> 5, j = tid & 31;
        if (j < 24) {
#pragma unroll 1
          for (int t = slot; t < L; t += 4)
            s_g[t * 24 + j] = gpb[j] + dotv<6>(gpw + j * 24, s_h + t * 24);
        }
      }
      __syncthreads();
      // ---- GRU, 2 layers
      const float* srcp = s_g;
#pragma unroll 1
      for (int l = 0; l < 2; ++l) {
        const int nl = n * 2 + l;
        const float* wih = gru_wih + (size_t)nl * 72 * 24;
        const float* bih = gru_bih + nl * 72;
        // input gates: lane = row, waves split the t axis
        {
          float4 WA[6], WB[6];
          const float4* wa = reinterpret_cast<const float4*>(wih + (size_t)lane * 24);
          const float4* wb = reinterpret_cast<const float4*>(
              wih + (size_t)(64 + (lane & 7)) * 24);
#pragma unroll
          for (int i = 0; i < 6; ++i) { WA[i] = wa[i]; WB[i] = wb[i]; }
          float bA = bih[lane];
          float bB = bih[64 + (lane & 7)];
#pragma unroll 1
          for (int t = wid; t < L; t += 2) {
            const float4* h4 = reinterpret_cast<const float4*>(srcp + t * 24);
            float accA = bA, accB = bB;
#pragma unroll
            for (int i = 0; i < 6; ++i) {
              float4 hh = h4[i];
              accA = fmaf(WA[i].x, hh.x, accA); accA = fmaf(WA[i].y, hh.y, accA);
              accA = fmaf(WA[i].z, hh.z, accA); accA = fmaf(WA[i].w, hh.w, accA);
              accB = fmaf(WB[i].x, hh.x, accB); accB = fmaf(WB[i].y, hh.y, accB);
              accB = fmaf(WB[i].z, hh.z, accB); accB = fmaf(WB[i].w, hh.w, accB);
            }
            s_gi[t * 72 + lane] = accA;
            if (lane < 8) s_gi[t * 72 + 64 + lane] = accB;
          }
        }
        __syncthreads();
        // hidden recurrence: wave 0 only, half-split (lanes j and j+32 each
        // take 12 of 24 inputs, combine with shfl_xor(32)). No barriers
        // inside: single-wave DS ops are compiler-ordered.
        if (wid == 0) {
          const float* whh = gru_whh + (size_t)nl * 72 * 24;
          const float* bhh = gru_bhh + nl * 72;
          int jm = lane & 31, half = lane >> 5;
          int jq = jm < 24 ? jm : 0;  // clamp for inactive lanes
          float4 Wr[3], Wz[3], Wn[3];
          {
            const float4* wr4 = reinterpret_cast<const float4*>(whh + jq * 24 + half * 12);
            const float4* wz4 = reinterpret_cast<const float4*>(whh + (24 + jq) * 24 + half * 12);
            const float4* wn4 = reinterpret_cast<const float4*>(whh + (48 + jq) * 24 + half * 12);
#pragma unroll
            for (int i = 0; i < 3; ++i) { Wr[i] = wr4[i]; Wz[i] = wz4[i]; Wn[i] = wn4[i]; }
          }
          // bias counted ONCE: half 1 starts its partials at 0 (round-4 bug fix)
          float bR = half ? 0.0f : bhh[jq];
          float bZ = half ? 0.0f : bhh[24 + jq];
          float bN = half ? 0.0f : bhh[48 + jq];
          if (lane < 24) s_hid[lane] = 0.0f;
          int cur = 0;
#pragma unroll 1
          for (int t = 0; t < L; ++t) {
            const float4* hp = reinterpret_cast<const float4*>(
                s_hid + cur * 24 + half * 12);
            float gr = bR, gz = bZ, gn = bN;
#pragma unroll
            for (int i = 0; i < 3; ++i) {
              float4 hh = hp[i];
              gr = fmaf(Wr[i].x, hh.x, gr); gr = fmaf(Wr[i].y, hh.y, gr);
              gr = fmaf(Wr[i].z, hh.z, gr); gr = fmaf(Wr[i].w, hh.w, gr);
              gz = fmaf(Wz[i].x, hh.x, gz); gz = fmaf(Wz[i].y, hh.y, gz);
              gz = fmaf(Wz[i].z, hh.z, gz); gz = fmaf(Wz[i].w, hh.w, gz);
              gn = fmaf(Wn[i].x, hh.x, gn); gn = fmaf(Wn[i].y, hh.y, gn);
              gn = fmaf(Wn[i].z, hh.z, gn); gn = fmaf(Wn[i].w, hh.w, gn);
            }
            gr += __shfl_xor(gr, 32);
            gz += __shfl_xor(gz, 32);
            gn += __shfl_xor(gn, 32);
            const float* gi = s_gi + t * 72;
            float r   = sigm(gi[jq] + gr);
            float zg  = sigm(gi[24 + jq] + gz);
            float nn2 = tanh_fast(gi[48 + jq] + r * gn);
            float hold = s_hid[cur * 24 + jq];
            float hnew = fmaf(zg, hold - nn2, nn2);  // (1-z)*n + z*h
            if (lane < 24) {
              s_hid[(cur ^ 1) * 24 + lane] = hnew;
              s_y[t * 24 + lane] = hnew;
            }
            cur ^= 1;
          }
        }
        __syncthreads();
        srcp = s_y;
      }
      // ---- causal map layer 1: lane = j (64 outputs), waves split t
      {
        float4 W[6];
        const float4* w4 = reinterpret_cast<const float4*>(
            cm_w1 + (size_t)(n * 64 + lane) * 24);
#pragma unroll
        for (int i = 0; i < 6; ++i) W[i] = w4[i];
        float bb = cm_b1[n * 64 + lane];
#pragma unroll 1
        for (int t = wid; t < L; t += 2) {
          const float4* y4 = reinterpret_cast<const float4*>(s_y + t * 24);
          float acc = bb;
#pragma unroll
          for (int i = 0; i < 6; ++i) {
            float4 hh = y4[i];
            acc = fmaf(W[i].x, hh.x, acc); acc = fmaf(W[i].y, hh.y, acc);
            acc = fmaf(W[i].z, hh.z, acc); acc = fmaf(W[i].w, hh.w, acc);
          }
          s_d1[t * 68 + lane] = fmaxf(acc, 0.0f);
        }
      }
      __syncthreads();
      // ---- causal map layer 2: lane = j (64 outputs), waves split t
      {
        float4 W[16];
        const float4* w4 = reinterpret_cast<const float4*>(
            cm_w2 + (size_t)(n * 64 + lane) * 64);
#pragma unroll
        for (int i = 0; i < 16; ++i) W[i] = w4[i];
        float bb = cm_b2[n * 64 + lane];
#pragma unroll 1
        for (int t = wid; t < L; t += 2) {
          const float4* d4 = reinterpret_cast<const float4*>(s_d1 + t * 68);
          float acc = bb;
#pragma unroll
          for (int i = 0; i < 16; ++i) {
            float4 hh = d4[i];
            acc = fmaf(W[i].x, hh.x, acc); acc = fmaf(W[i].y, hh.y, acc);
            acc = fmaf(W[i].z, hh.z, acc); acc = fmaf(W[i].w, hh.w, acc);
          }
          s_d2[t * 68 + lane] = fmaxf(acc, 0.0f);
        }
      }
      __syncthreads();
      // ---- causal map layer 3 -> decoded + emit (w3 row is lane-uniform)
      if (wid == 0 && lane < L) {
        int t = lane;
        float dv = cm_b3[n] + dotv<16>(cm_w3 + n * 64, s_d2 + t * 68);
        s_dec[n * 8 + t] = dv;
        if (t == idx)
          out[((size_t)b * T + idx) * 8 + n] = dv;
      }
      __syncthreads();
    }
  }
}

extern "C" void kernel_launch(void* const* d_in, const int* in_sizes, int n_in,
                              void* d_out, int out_size, void* d_ws, size_t ws_size,
                              hipStream_t stream) {
  const float* z       = (const float*)d_in[0];
  const float* cond_w1 = (const float*)d_in[1];
  const float* cond_b1 = (const float*)d_in[2];
  const float* cond_w2 = (const float*)d_in[3];
  const float* cond_b2 = (const float*)d_in[4];
  const float* proj_w  = (const float*)d_in[5];
  const float* proj_b  = (const float*)d_in[6];
  const float* gpw     = (const float*)d_in[7];
  const float* gpb     = (const float*)d_in[8];
  const float* gru_wih = (const float*)d_in[9];
  const float* gru_whh = (const float*)d_in[10];
  const float* gru_bih = (const float*)d_in[11];
  const float* gru_bhh = (const float*)d_in[12];
  const float* cm_w1   = (const float*)d_in[13];
  const float* cm_b1   = (const float*)d_in[14];
  const float* cm_w2   = (const float*)d_in[15];
  const float* cm_b2   = (const float*)d_in[16];
  const float* cm_w3   = (const float*)d_in[17];
  const float* cm_b3   = (const float*)d_in[18];
  const int*   endw    = (const int*)d_in[19];
  float* out = (float*)d_out;

  int Btot = in_sizes[0] / (8 * 8 * 32);  // z: [8, B, 8, 32]

  tcm_kernel<<<Btot, NT, 0, stream>>>(
      z, cond_w1, cond_b1, cond_w2, cond_b2, proj_w, proj_b, gpw, gpb,
      gru_wih, gru_whh, gru_bih, gru_bhh, cm_w1, cm_b1, cm_w2, cm_b2,
      cm_w3, cm_b3, endw, out, Btot);
}